// Round 12
// baseline (131.218 us; speedup 1.0000x reference)
//
#include <hip/hip_runtime.h>
#include <hip/hip_fp16.h>

// msg[e] = src_emb[src_idx[e]] * e_att[e]; out = segment_sum(msg, dst_idx, N_DST)
// src_emb [50000,64] f32, e_att [800000,1] f32, src_idx/dst_idx [800000] i32,
// out [50000,64] f32.
//
// R12 = R11 with split buckets: each dst bucket = two 32-slot halves (A/B)
// chosen by edge parity; separate cursorA/cursorB arrays -> same-address
// atomic chains halve (16 -> ~8 per address, two independent addresses).
// Scatter XCD-partitioned (blockIdx&7 = partition; payload region 1.6MB/XCD,
// L2-resident). Convert f32->f16 fused into scatter grid. Gather: 2 dst
// rows/wave, two 32-slot segments, __half2 4B/lane loads, 4-slot unroll.

#define D 64
#define CAP 64              // total slots per dst bucket (2 x 32)
#define HCAP 32             // slots per half; half-deg ~ Binom(deg,1/2), mean 8
#define OVF_CAP 65536
#define NPART 8

// ---------------- fused scatter + convert ----------------
__global__ void __launch_bounds__(256)
scatter_conv_kernel(const int* __restrict__ dst_idx, const int* __restrict__ src_idx,
                    const float* __restrict__ e_att,
                    int* __restrict__ cursorA, int* __restrict__ cursorB,
                    unsigned* __restrict__ payload,
                    int* __restrict__ ovf_count, int* __restrict__ ovf_list,
                    const float* __restrict__ src_emb, __half* __restrict__ emb_h,
                    int E, int n_dst, int rpx, int epb4, int SB, int n4) {
    if ((int)blockIdx.x >= SB) {
        // ---- convert role: f32 -> f16, 4 elems/thread
        int i = ((int)blockIdx.x - SB) * 256 + threadIdx.x;
        if (i < n4) {
            float4 v = ((const float4*)src_emb)[i];
            ushort4 h;
            h.x = __half_as_ushort(__float2half(v.x));
            h.y = __half_as_ushort(__float2half(v.y));
            h.z = __half_as_ushort(__float2half(v.z));
            h.w = __half_as_ushort(__float2half(v.w));
            ((ushort4*)emb_h)[i] = h;
        }
        return;
    }

    // ---- scatter role
    int x     = blockIdx.x & (NPART - 1);   // dst partition == target XCD
    int chunk = blockIdx.x >> 3;
    int lo  = x * rpx;
    int hi  = min(lo + rpx, n_dst);
    unsigned span = (unsigned)(hi - lo);

    int E4 = E >> 2;
    int i0 = chunk * epb4;
    int i1 = min(i0 + epb4, E4);

    for (int i = i0 + threadIdx.x; i < i1; i += 256) {
        int4 d4 = ((const int4*)dst_idx)[i];
        bool m0 = (unsigned)(d4.x - lo) < span;
        bool m1 = (unsigned)(d4.y - lo) < span;
        bool m2 = (unsigned)(d4.z - lo) < span;
        bool m3 = (unsigned)(d4.w - lo) < span;
        if (!(m0 | m1 | m2 | m3)) continue;     // skip src/att loads entirely
        int4   s4 = ((const int4*)src_idx)[i];
        float4 a4 = ((const float4*)e_att)[i];
        int   dd[4] = {d4.x, d4.y, d4.z, d4.w};
        int   ss[4] = {s4.x, s4.y, s4.z, s4.w};
        float aa[4] = {a4.x, a4.y, a4.z, a4.w};
        bool  mm[4] = {m0, m1, m2, m3};
#pragma unroll
        for (int k = 0; k < 4; ++k) {
            if (!mm[k]) continue;
            int d = dd[k];
            // half select: edge parity (4*i+k -> parity = k&1), compile-time per k
            int* cur = (k & 1) ? cursorB : cursorA;
            int p = atomicAdd(&cur[d], 1);
            unsigned pay = (unsigned)ss[k] |
                           ((unsigned)__half_as_ushort(__float2half(aa[k])) << 16);
            if (p < HCAP) {
                payload[(size_t)d * CAP + ((k & 1) << 5) + p] = pay;  // L2-local
            } else {
                int oi = atomicAdd(ovf_count, 1);
                if (oi < OVF_CAP) ovf_list[oi] = 4 * i + k;
            }
        }
    }
    // tail (E % 4 edges): chunk 0 of every partition, scalar
    if (chunk == 0) {
        for (int e = (E4 << 2) + threadIdx.x; e < E; e += 256) {
            int d = dst_idx[e];
            if ((unsigned)(d - lo) >= span) continue;
            int h = e & 1;
            int* cur = h ? cursorB : cursorA;
            int p = atomicAdd(&cur[d], 1);
            unsigned pay = (unsigned)src_idx[e] |
                           ((unsigned)__half_as_ushort(__float2half(e_att[e])) << 16);
            if (p < HCAP) payload[(size_t)d * CAP + (h << 5) + p] = pay;
            else { int oi = atomicAdd(ovf_count, 1); if (oi < OVF_CAP) ovf_list[oi] = e; }
        }
    }
}

// ---------------- gather: 2 dst rows per wave, 2 x 32-slot segments ----------------
__global__ void __launch_bounds__(256)
gather2_kernel(const __half* __restrict__ emb_h,
               const unsigned* __restrict__ payload,
               const int* __restrict__ cursorA, const int* __restrict__ cursorB,
               const int* __restrict__ dst_idx, const int* __restrict__ src_idx,
               const float* __restrict__ e_att, const float* __restrict__ src_emb,
               const int* __restrict__ ovf_count, const int* __restrict__ ovf_list,
               float* __restrict__ out, int n_dst, int n_src, int rpx) {
    int x    = blockIdx.x & (NPART - 1);
    int g    = blockIdx.x >> 3;
    int wv   = threadIdx.x >> 6;            // wave in block (0..3)
    int lane = threadIdx.x & 63;
    int sub  = lane >> 5;                   // 0/1: which of the wave's 2 rows
    int l31  = lane & 31;                   // column-pair owner

    int local = (g * 4 + wv) * 2 + sub;     // row within partition
    int w = x * rpx + local;
    bool rowvalid = (local < rpx) && (w < n_dst);

    int cnA = rowvalid ? cursorA[w] : 0;
    int cnB = rowvalid ? cursorB[w] : 0;
    int cA = min(cnA, HCAP);
    int cB = min(cnB, HCAP);

    // preload: lane l31 holds slot l31 of each 32-slot segment
    unsigned ppA = 0u, ppB = 0u;
    if (rowvalid) {
        ppA = payload[(size_t)w * CAP + l31];
        ppB = payload[(size_t)w * CAP + 32 + l31];
    }

    int cmaxA = max(cA, __shfl_xor(cA, 32));
    int cmaxB = max(cB, __shfl_xor(cB, 32));

    float2 acc = make_float2(0.f, 0.f);
    unsigned smax = (unsigned)(n_src - 1);

#define GATHER_SEG(pp, cc, cmax)                                                        \
    for (int j = 0; j < cmax; j += 4) {                                                 \
        int sl = (sub << 5) + j;                                                        \
        unsigned pv0 = (unsigned)__shfl((int)pp, sl);                                   \
        unsigned pv1 = (unsigned)__shfl((int)pp, sl + 1);                               \
        unsigned pv2 = (unsigned)__shfl((int)pp, sl + 2);                               \
        unsigned pv3 = (unsigned)__shfl((int)pp, sl + 3);                               \
        float a0 = (j     < cc) ? __half2float(__ushort_as_half((unsigned short)(pv0 >> 16))) : 0.f; \
        float a1 = (j + 1 < cc) ? __half2float(__ushort_as_half((unsigned short)(pv1 >> 16))) : 0.f; \
        float a2 = (j + 2 < cc) ? __half2float(__ushort_as_half((unsigned short)(pv2 >> 16))) : 0.f; \
        float a3 = (j + 3 < cc) ? __half2float(__ushort_as_half((unsigned short)(pv3 >> 16))) : 0.f; \
        unsigned s0 = min(pv0 & 0xffffu, smax);                                         \
        unsigned s1 = min(pv1 & 0xffffu, smax);                                         \
        unsigned s2 = min(pv2 & 0xffffu, smax);                                         \
        unsigned s3 = min(pv3 & 0xffffu, smax);                                         \
        __half2 h0 = ((const __half2*)(emb_h + (size_t)s0 * D))[l31];                   \
        __half2 h1 = ((const __half2*)(emb_h + (size_t)s1 * D))[l31];                   \
        __half2 h2 = ((const __half2*)(emb_h + (size_t)s2 * D))[l31];                   \
        __half2 h3 = ((const __half2*)(emb_h + (size_t)s3 * D))[l31];                   \
        acc.x = fmaf(__low2float(h0),  a0, acc.x);                                      \
        acc.y = fmaf(__high2float(h0), a0, acc.y);                                      \
        acc.x = fmaf(__low2float(h1),  a1, acc.x);                                      \
        acc.y = fmaf(__high2float(h1), a1, acc.y);                                      \
        acc.x = fmaf(__low2float(h2),  a2, acc.x);                                      \
        acc.y = fmaf(__high2float(h2), a2, acc.y);                                      \
        acc.x = fmaf(__low2float(h3),  a3, acc.x);                                      \
        acc.y = fmaf(__high2float(h3), a3, acc.y);                                      \
    }

    GATHER_SEG(ppA, cA, cmaxA)
    GATHER_SEG(ppB, cB, cmaxB)
#undef GATHER_SEG

    if (rowvalid) {
        // insurance: half-bucket overflow (expected never). Exact f32 path.
        if ((cnA > HCAP) | (cnB > HCAP)) {
            int oc = *ovf_count;
            if (oc > OVF_CAP) oc = OVF_CAP;
            for (int i = 0; i < oc; ++i) {
                int e = ovf_list[i];
                if (dst_idx[e] == w) {
                    float a = e_att[e];
                    int   s = src_idx[e];
                    acc.x = fmaf(src_emb[(size_t)s * D + 2 * l31],     a, acc.x);
                    acc.y = fmaf(src_emb[(size_t)s * D + 2 * l31 + 1], a, acc.y);
                }
            }
        }
        ((float2*)(out + (size_t)w * D))[l31] = acc;   // wave store: 512B over 2 rows
    }
}

// ---------------- fallback: pure atomic ----------------
__global__ void __launch_bounds__(256)
atomic_fallback_kernel(const float* __restrict__ src_emb, const float* __restrict__ e_att,
                       const int* __restrict__ src_idx, const int* __restrict__ dst_idx,
                       float* __restrict__ out, int E) {
    int tid  = blockIdx.x * blockDim.x + threadIdx.x;
    int e    = tid >> 4;
    int part = tid & 15;
    if (e >= E) return;
    int   s = src_idx[e];
    int   d = dst_idx[e];
    float a = e_att[e];
    float4 v = ((const float4*)src_emb)[(size_t)s * 16 + part];
    float* orow = out + (size_t)d * D + part * 4;
    atomicAdd(orow + 0, v.x * a);
    atomicAdd(orow + 1, v.y * a);
    atomicAdd(orow + 2, v.z * a);
    atomicAdd(orow + 3, v.w * a);
}

extern "C" void kernel_launch(void* const* d_in, const int* in_sizes, int n_in,
                              void* d_out, int out_size, void* d_ws, size_t ws_size,
                              hipStream_t stream) {
    const float* src_emb = (const float*)d_in[0];
    const float* e_att   = (const float*)d_in[1];
    const int*   src_idx = (const int*)d_in[2];
    const int*   dst_idx = (const int*)d_in[3];
    float*       out     = (float*)d_out;

    const int E     = in_sizes[2];       // 800000
    const int n_dst = out_size / D;      // 50000
    const int n_src = in_sizes[0] / D;   // 50000

    // ws layout (4B units): emb_h[n_src*D/2] | payload[n_dst*CAP] |
    //   cursorA[n_dst] | cursorB[n_dst] | ovf_count[1] | ovf_list[OVF_CAP]
    size_t off_emb  = 0;
    size_t off_pay  = off_emb + (size_t)n_src * D / 2;
    size_t off_curA = off_pay + (size_t)n_dst * CAP;
    size_t off_curB = off_curA + (size_t)n_dst;
    size_t need_ints = off_curB + (size_t)n_dst + 1 + OVF_CAP;

    if (n_src <= 65536 && ws_size >= need_ints * sizeof(int)) {
        __half*   emb_h   = (__half*)d_ws;
        unsigned* payload = (unsigned*)d_ws + off_pay;
        int*      cursorA = (int*)d_ws + off_curA;
        int*      cursorB = (int*)d_ws + off_curB;
        int*      ovf_count = cursorB + n_dst;
        int*      ovf_list  = ovf_count + 1;

        // zero cursorA + cursorB + ovf_count (contiguous, ~400 KB)
        hipMemsetAsync(cursorA, 0, (2 * (size_t)n_dst + 1) * sizeof(int), stream);

        const int rpx = (n_dst + NPART - 1) / NPART;   // 6250 dst rows/partition
        const int chunks = 512;
        const int SB = chunks * NPART;                 // scatter blocks
        const int E4 = E >> 2;
        const int epb4 = (E4 + chunks - 1) / chunks;
        const int n4 = n_src * D / 4;
        const int CB = (n4 + 255) / 256;               // convert blocks

        scatter_conv_kernel<<<SB + CB, 256, 0, stream>>>(
            dst_idx, src_idx, e_att, cursorA, cursorB, payload, ovf_count,
            ovf_list, src_emb, emb_h, E, n_dst, rpx, epb4, SB, n4);

        const int gpb = (rpx + 7) / 8;                 // 8 rows per block (4 waves x 2)
        gather2_kernel<<<gpb * NPART, 256, 0, stream>>>(
            emb_h, payload, cursorA, cursorB, dst_idx, src_idx, e_att, src_emb,
            ovf_count, ovf_list, out, n_dst, n_src, rpx);
        return;
    }

    // fallback: pure atomic
    hipMemsetAsync(d_out, 0, (size_t)out_size * sizeof(float), stream);
    atomic_fallback_kernel<<<(E * 16 + 255) / 256, 256, 0, stream>>>(
        src_emb, e_att, src_idx, dst_idx, out, E);
}